// Round 6
// baseline (480.402 us; speedup 1.0000x reference)
//
#include <hip/hip_runtime.h>
#include <cstddef>

#define A_  5
#define C_  12
#define RPG (C_ * A_)                 // (coil,a) planes = 60
#define TWO_PI 6.28318530717958647692f

// ---------------------------------------------------------------------------
// Pipeline R6 (wave-synchronous register FFT, 3 kernels, all global I/O
// full-line):
//   k_fft1c : per (ca, x-octet): 8 y-FFTs (one per xcol) in registers,
//             gather x/mps from native layout (L3-resident), stage through
//             a [8 xc][520 ky] LDS tile, write bufA[ca][ky][x] full lines.
//   k_colfmc: per (coil,ky), ONE WAVE: 5 fwd x-FFTs (coalesced row reads,
//             F spectra in 80 VGPRs) + pointwise mix with native-layout
//             kern (scale folded) + 5 inv x-FFTs, coalesced row writes to
//             bufB[ca][ky][x].  No barriers at all.
//   k_outfr : per (a,xcol), 4 waves x 3 coils: ky-FFTs from full-line
//             gathers of bufB (XCD-pinned xcol octets), conj(mps) reduce
//             across waves in LDS, planar out writes (L2-merged).
// FFT: 512 = 8^3. Lane L holds 8 elems. Stage = in-register 8-pt DFT;
// 2 LDS shuffles (pitch 72 / 9*d+f -- every access <=2-way on banks);
// no barriers (single-wave in-order DS). Digit-swap sigma(L)=8(L&7)+(L>>3)
// handled by lane-relabeling: fwd lh=L (natural in, swapped out), inv
// lh=sigma(L) (swapped in, natural out). Swapped order flows through the
// pointwise mix at zero cost.
// ---------------------------------------------------------------------------
__device__ float2 g_bufA[RPG * 512 * 256];  // 63 MB  [ca][ky][x]
__device__ float2 g_bufB[RPG * 512 * 256];  // 63 MB  [ca][ky][x]

// ---- in-register 8-point DFT (DIF), natural-order input AND output ----
template<int DIR>
__device__ __forceinline__ void dft8(float* xr, float* xi) {
    const float S = 0.70710678118654752f;
    float ar[4], ai[4], br[4], bi[4];
#pragma unroll
    for (int j = 0; j < 4; ++j) {
        ar[j] = xr[j] + xr[j+4]; ai[j] = xi[j] + xi[j+4];
        br[j] = xr[j] - xr[j+4]; bi[j] = xi[j] - xi[j+4];
    }
    float t;
    if (DIR < 0) {                       // W8^1=(S,-S) W8^2=-i W8^3=(-S,-S)
        t = S*(br[1]+bi[1]); bi[1] = S*(bi[1]-br[1]); br[1] = t;
        t = bi[2];           bi[2] = -br[2];          br[2] = t;
        t = S*(bi[3]-br[3]); bi[3] = -S*(br[3]+bi[3]); br[3] = t;
    } else {                             // conjugates
        t = S*(br[1]-bi[1]); bi[1] = S*(bi[1]+br[1]); br[1] = t;
        t = -bi[2];          bi[2] = br[2];           br[2] = t;
        t = -S*(br[3]+bi[3]); bi[3] = S*(br[3]-bi[3]); br[3] = t;
    }
    float c0r=ar[0]+ar[2], c0i=ai[0]+ai[2], c1r=ar[1]+ar[3], c1i=ai[1]+ai[3];
    float d0r=ar[0]-ar[2], d0i=ai[0]-ai[2], d1r, d1i;
    if (DIR < 0) { d1r =  ai[1]-ai[3]; d1i = -(ar[1]-ar[3]); }
    else         { d1r = -(ai[1]-ai[3]); d1i =  ar[1]-ar[3]; }
    xr[0]=c0r+c1r; xi[0]=c0i+c1i; xr[4]=c0r-c1r; xi[4]=c0i-c1i;
    xr[2]=d0r+d1r; xi[2]=d0i+d1i; xr[6]=d0r-d1r; xi[6]=d0i-d1i;
    c0r=br[0]+br[2]; c0i=bi[0]+bi[2]; c1r=br[1]+br[3]; c1i=bi[1]+bi[3];
    d0r=br[0]-br[2]; d0i=bi[0]-bi[2];
    if (DIR < 0) { d1r =  bi[1]-bi[3]; d1i = -(br[1]-br[3]); }
    else         { d1r = -(bi[1]-bi[3]); d1i =  br[1]-br[3]; }
    xr[1]=c0r+c1r; xi[1]=c0i+c1i; xr[5]=c0r-c1r; xi[5]=c0i-c1i;
    xr[3]=d0r+d1r; xi[3]=d0i+d1i; xr[7]=d0r-d1r; xi[7]=d0i-d1i;
}

// v[d] *= cis(ang)^d, d=1..7 (chained; base from one __sincosf)
__device__ __forceinline__ void twiddle_chain(float* vr, float* vi, float ang) {
    float s, c; __sincosf(ang, &s, &c);
    float twr = c, twi = s;
#pragma unroll
    for (int d = 1; d < 8; ++d) {
        float tr = vr[d]*twr - vi[d]*twi;
        vi[d]    = vr[d]*twi + vi[d]*twr;
        vr[d]    = tr;
        float nr = twr*c - twi*s;
        twi      = twr*s + twi*c;
        twr      = nr;
    }
}

// Wave-synchronous 512-pt FFT. Input: reg a holds X[64a + lh].
// Output: reg g holds Y[64g + 8*(lh&7) + (lh>>3)].
// sre/sim: per-wave scratch, 576 floats each. NO barriers (single wave).
template<int DIR>
__device__ __forceinline__ void wfft512(float* vr, float* vi,
                                        float* sre, float* sim, int lh) {
    const float sgn = (DIR < 0) ? -1.f : 1.f;
    dft8<DIR>(vr, vi);
    twiddle_chain(vr, vi, sgn * (TWO_PI/512.f) * (float)lh);
#pragma unroll
    for (int d = 0; d < 8; ++d) { sre[72*d+lh] = vr[d]; sim[72*d+lh] = vi[d]; }
    asm volatile("s_waitcnt lgkmcnt(0)" ::: "memory");
    int rb = 72*(lh>>3) + (lh&7);
#pragma unroll
    for (int e = 0; e < 8; ++e) { vr[e] = sre[rb+8*e]; vi[e] = sim[rb+8*e]; }
    dft8<DIR>(vr, vi);
    twiddle_chain(vr, vi, sgn * (TWO_PI/64.f) * (float)(lh & 7));
    int wb = 9*(lh>>3) + (lh&7);
#pragma unroll
    for (int h = 0; h < 8; ++h) { sre[72*h+wb] = vr[h]; sim[72*h+wb] = vi[h]; }
    asm volatile("s_waitcnt lgkmcnt(0)" ::: "memory");
    int rb2 = 72*(lh&7) + 9*(lh>>3);
#pragma unroll
    for (int f = 0; f < 8; ++f) { vr[f] = sre[rb2+f]; vi[f] = sim[rb2+f]; }
    dft8<DIR>(vr, vi);
}

// ---------------------------------------------------------------------------
// Pass 1: per (ca, x-octet): modulate mps*x (gathers; inputs are 8.5 MB ->
// L3-resident), pad y in registers, 8 wave-FFTs along y (wave w does
// xc = w, w+4), stage to LDS tile[xc][ky], cooperative full-line write of
// bufA[ca][ky][x0..x0+7].
// ---------------------------------------------------------------------------
__global__ void __launch_bounds__(256) k_fft1c(const float* __restrict__ xr_,
        const float* __restrict__ xi_, const float* __restrict__ mr_,
        const float* __restrict__ mi_) {
    __shared__ float2 tile[8][520];          // 33.3 KB, pitch 520 (bank-safe)
    __shared__ float shR[4][576], shI[4][576];
    int bid = blockIdx.x;
    int ca = bid >> 5, oct = bid & 31, x0 = oct << 3;
    int coil = ca / A_, aS = ca % A_;
    int tid = threadIdx.x, w = tid >> 6, L = tid & 63;
    int sig = ((L & 7) << 3) | (L >> 3);
    float* sre = shR[w]; float* sim = shI[w];
    const float* xr = xr_ + aS * 65536;
    const float* xi = xi_ + aS * 65536;
    const float* mr = mr_ + coil * 65536;
    const float* mi = mi_ + coil * 65536;
#pragma unroll
    for (int pass = 0; pass < 2; ++pass) {
        int xc = w + 4 * pass;               // 0..7
        int xcol = x0 + xc;
        float vr[8], vi[8];
#pragma unroll
        for (int r = 0; r < 8; ++r) { vr[r] = 0.f; vi[r] = 0.f; }
#pragma unroll
        for (int r = 2; r < 6; ++r) {        // y5 = 64r + L in [128,384)
            int y = ((r - 2) << 6) + L;
            int idx = y * 256 + xcol;
            float xrv = xr[idx], xiv = xi[idx], mrv = mr[idx], miv = mi[idx];
            vr[r] = xrv * mrv - xiv * miv;
            vi[r] = xrv * miv + xiv * mrv;
        }
        wfft512<-1>(vr, vi, sre, sim, L);    // out: ky = 64g + sig
#pragma unroll
        for (int g = 0; g < 8; ++g)
            tile[xc][(g << 6) + sig] = make_float2(vr[g], vi[g]);
    }
    __syncthreads();
    int xcW = tid & 7, kyo = tid >> 3;       // 8 xc x 32 ky per iter
    float2* orow = g_bufA + (size_t)ca * 131072 + x0 + xcW;
#pragma unroll
    for (int rr = 0; rr < 16; ++rr) {
        int ky = (rr << 5) + kyo;
        orow[(size_t)ky << 8] = tile[xcW][ky];   // 8x 64B full lines / instr
    }
}

// ---------------------------------------------------------------------------
// Pass 2 (fused): per (coil,ky), ONE wave, zero barriers.
//   5 fwd x-FFTs (coalesced bufA row reads, pad in regs, F in 80 VGPRs)
//   mix: G[ao] = scale * sum_ain kern[ao*5+ain][ky][kx] * F[ain], pointwise
//        in the swapped kx order (kx = 64g + sig); K rows L2-shared by the
//        12 coil-blocks of this ky (XCD-pinned swizzle).
//   5 inv x-FFTs (lh = sig -> natural x out), crop, coalesced row writes.
// ---------------------------------------------------------------------------
__global__ void __launch_bounds__(64, 3) k_colfmc(const float* __restrict__ kr,
                                                  const float* __restrict__ ki) {
    __shared__ float sre[576], sim[576];
    int b = blockIdx.x;
    int xcd = b & 7, s = b >> 3;             // bijective XCD-cluster swizzle
    int v = s / 96, wv = s % 96;
    int u = xcd + (v << 3);                  // ky-octet 0..63
    int coil = wv % C_;
    int ky = (u << 3) + (wv / C_);
    int L = threadIdx.x & 63;
    int sig = ((L & 7) << 3) | (L >> 3);
    float Fr[A_][8], Fi[A_][8];
    const float2* bA = g_bufA + (size_t)(coil * A_) * 131072 + ((size_t)ky << 8);
#pragma unroll
    for (int ain = 0; ain < A_; ++ain) {
        const float2* row = bA + (size_t)ain * 131072;
#pragma unroll
        for (int r = 0; r < 8; ++r) { Fr[ain][r] = 0.f; Fi[ain][r] = 0.f; }
#pragma unroll
        for (int r = 2; r < 6; ++r) {        // x5 = 64r + L in [128,384)
            float2 vv = row[((r - 2) << 6) + L];
            Fr[ain][r] = vv.x; Fi[ain][r] = vv.y;
        }
        wfft512<-1>(Fr[ain], Fi[ain], sre, sim, L);  // F at kx = 64g + sig
    }
    const float scale = 4.0f / 262144.0f;    // OVERSAMP^2 / (Hp*Wp)
    size_t kbase = (size_t)ky << 9;
#pragma unroll
    for (int g = 0; g < 8; ++g) {
        size_t kxo = kbase + (size_t)((g << 6) + sig);
        float gr[A_], gi[A_];
#pragma unroll
        for (int ao = 0; ao < A_; ++ao) {
            float ar = 0.f, ai = 0.f;
#pragma unroll
            for (int ain = 0; ain < A_; ++ain) {
                size_t idx = ((size_t)(ao * A_ + ain) << 18) + kxo;
                float kre = kr[idx], kim = ki[idx];
                ar += kre * Fr[ain][g] - kim * Fi[ain][g];
                ai += kre * Fi[ain][g] + kim * Fr[ain][g];
            }
            gr[ao] = scale * ar; gi[ao] = scale * ai;
        }
#pragma unroll
        for (int ao = 0; ao < A_; ++ao) { Fr[ao][g] = gr[ao]; Fi[ao][g] = gi[ao]; }
    }
#pragma unroll
    for (int ao = 0; ao < A_; ++ao) {
        wfft512<1>(Fr[ao], Fi[ao], sre, sim, sig);   // natural x5 = 64g + L
        float2* oB = g_bufB + (size_t)(coil * A_ + ao) * 131072 + ((size_t)ky << 8);
#pragma unroll
        for (int g = 2; g < 6; ++g)                  // crop x5 in [128,384)
            oB[((g - 2) << 6) + L] = make_float2(Fr[ao][g], Fi[ao][g]);
    }
}

// ---------------------------------------------------------------------------
// Pass 3: per (a,xcol), 4 waves x 3 coils each: inverse ky-FFT from bufB
// gathers (lines [ky][8x] fully consumed; xcol-octet XCD-pinned), crop y,
// conj(mps) multiply-accumulate, cross-wave LDS reduce, planar out write
// (4B scatter; out lines complete within L2 -> no amplification).
// ---------------------------------------------------------------------------
__global__ void __launch_bounds__(256) k_outfr(const float* __restrict__ mr_,
        const float* __restrict__ mi_, float* __restrict__ out, int outFloats) {
    __shared__ float shR[4][576], shI[4][576];
    __shared__ float red[3][64][9];          // pitch 9: bank-safe
    int b = blockIdx.x;
    int xcd = b & 7, s = b >> 3;             // bijective: octet -> XCD
    int u = xcd + ((s >> 3) << 3);           // 0..159 = (a, octet)
    int off = s & 7;
    int aS = u >> 5;
    int xcol = ((u & 31) << 3) + off;
    int tid = threadIdx.x, w = tid >> 6, L = tid & 63;
    int sig = ((L & 7) << 3) | (L >> 3);
    float* sre = shR[w]; float* sim = shI[w];
    float accr[4] = {0.f,0.f,0.f,0.f}, acci[4] = {0.f,0.f,0.f,0.f};
#pragma unroll
    for (int cc = 0; cc < 3; ++cc) {
        int c = w + (cc << 2);               // wave w: coils w, w+4, w+8
        const float2* src = g_bufB + (size_t)(c * A_ + aS) * 131072 + xcol;
        float vr[8], vi[8];
#pragma unroll
        for (int r = 0; r < 8; ++r) {        // ky = 64r + sig (swapped in)
            float2 vv = src[(size_t)((r << 6) + sig) << 8];
            vr[r] = vv.x; vi[r] = vv.y;
        }
        wfft512<1>(vr, vi, sre, sim, sig);   // natural y5 = 64g + L
        const float* mr = mr_ + c * 65536;
        const float* mi = mi_ + c * 65536;
#pragma unroll
        for (int g = 2; g < 6; ++g) {        // crop y5 in [128,384)
            int y = ((g - 2) << 6) + L;
            int idx = y * 256 + xcol;
            float mrv = mr[idx], miv = mi[idx];
            accr[g-2] += vr[g] * mrv + vi[g] * miv;   // v * conj(m)
            acci[g-2] += vi[g] * mrv - vr[g] * miv;
        }
    }
    if (w > 0) {
#pragma unroll
        for (int k = 0; k < 4; ++k) {
            red[w-1][L][k]   = accr[k];
            red[w-1][L][k+4] = acci[k];
        }
    }
    __syncthreads();
    if (w == 0) {
#pragma unroll
        for (int ww = 0; ww < 3; ++ww)
#pragma unroll
            for (int k = 0; k < 4; ++k) {
                accr[k] += red[ww][L][k];
                acci[k] += red[ww][L][k+4];
            }
#pragma unroll
        for (int k = 0; k < 4; ++k) {
            int y = (k << 6) + L;
            size_t r0 = (size_t)aS * 65536 + (size_t)y * 256 + xcol;
            size_t i0 = 327680 + r0;
            if (r0 < (size_t)outFloats) out[r0] = accr[k];
            if (i0 < (size_t)outFloats) out[i0] = acci[k];
        }
    }
}

// ---------------------------------------------------------------------------
extern "C" void kernel_launch(void* const* d_in, const int* in_sizes, int n_in,
                              void* d_out, int out_size, void* d_ws, size_t ws_size,
                              hipStream_t stream) {
    const float* xr = (const float*)d_in[0];
    const float* xi = (const float*)d_in[1];
    const float* mr = (const float*)d_in[2];
    const float* mi = (const float*)d_in[3];
    const float* kr = (const float*)d_in[4];
    const float* ki = (const float*)d_in[5];
    float* out = (float*)d_out;
    (void)d_ws; (void)ws_size; (void)n_in; (void)in_sizes;

    k_fft1c <<<RPG * 32, 256, 0, stream>>>(xr, xi, mr, mi);
    k_colfmc<<<C_ * 512, 64, 0, stream>>>(kr, ki);
    k_outfr <<<A_ * 256, 256, 0, stream>>>(mr, mi, out, out_size);
}

// Round 7
// 313.300 us; speedup vs baseline: 1.5334x; 1.5334x over previous
//
#include <hip/hip_runtime.h>
#include <cstddef>

#define A_  5
#define C_  12
#define RPG (C_ * A_)                 // (coil,a) planes = 60
#define TWO_PI 6.28318530717958647692f
#define NPAD 596                      // array stride: 20 mod 32 (cross-array spread)

// ---------------------------------------------------------------------------
// Pipeline R7 (batched 128-thread LDS FFT, derived conflict-free padding):
//   k_zero  : zero the planar output (outfr accumulates atomically)
//   k_fft1c : per (ca, x-quad): modulate mps*x, pad y, batch-4 y-FFTs,
//             write bufA[ca][ky][x] (32B x-chunks)
//   k_colfmc: per (coil,ky): coalesced bufA row reads, batch-5 fwd x-FFTs,
//             pointwise mix with NATIVE-layout kern (XCD-pinned L2 reuse,
//             K 2-deep software-pipelined), batch-5 inv x-FFTs, full-line
//             row writes to bufB[ca][ky][x]
//   k_outfr : per (a, x-quad, coil-triplet): batch-4 ky-IFFTs from bufB
//             (32B chunks, L3-resident), crop y, conj(mps) reduce,
//             atomicAdd into planar out
// Padding P5(i)=i+5*(i>>5): hand-enumerated banks for every stage pattern:
// reads/S3/r2 free, S0 2-way, S1 <=3-way on 4 banks, S2 2-way.
// ---------------------------------------------------------------------------
__device__ float2 g_bufA[RPG * 512 * 256];  // 63 MB [ca][ky][x]
__device__ float2 g_bufB[RPG * 512 * 256];  // 63 MB [ca][ky][x]

__device__ __forceinline__ int P5(int i) { return i + 5 * (i >> 5); }
__device__ __forceinline__ int PT(int i) { return i + (i >> 3); }

__device__ __forceinline__ void build_tab(float2* tab, int t) {
    #pragma unroll
    for (int q = 0; q < 2; ++q) {
        int k = t + q * 128;
        float s, c;
        __sincosf(-TWO_PI * (float)k * (1.0f / 512.0f), &s, &c);
        tab[PT(k)] = make_float2(c, s);
    }
}

template<int DIR>
__device__ __forceinline__ float2 cmulw(float2 v, float2 w) {
    float cv = w.x, sv = (DIR < 0) ? w.y : -w.y;   // DIR=+1 -> conj(w)
    return make_float2(v.x * cv - v.y * sv, v.x * sv + v.y * cv);
}

// Batched Stockham 512-pt FFT (4 radix-4 stages + radix-2), NB arrays,
// 128 threads, ~6 barriers total (vs 6*NB unbatched). Result in (BR,BI).
template<int DIR, int NB>
__device__ void fftB(float (*AR)[NPAD], float (*AI)[NPAD],
                     float (*BR)[NPAD], float (*BI)[NPAD],
                     const float2* tab, int t) {
    float (*sR)[NPAD] = AR; float (*sI)[NPAD] = AI;
    float (*dR)[NPAD] = BR; float (*dI)[NPAD] = BI;
    int Ns = 1;
    #pragma unroll
    for (int s = 0; s < 4; ++s) {
        __syncthreads();
        int m = t & (Ns - 1);
        int e1 = m << (7 - 2 * s);
        float2 w1 = tab[PT(e1)], w2 = tab[PT(2 * e1)];
        float2 w3 = make_float2(w1.x * w2.x - w1.y * w2.y,
                                w1.x * w2.y + w1.y * w2.x);
        int i0 = P5(t), i1 = P5(t + 128), i2 = P5(t + 256), i3 = P5(t + 384);
        int idxD = ((t & ~(Ns - 1)) << 2) | m;
        int o0 = P5(idxD), o1 = P5(idxD + Ns);
        int o2 = P5(idxD + 2 * Ns), o3 = P5(idxD + 3 * Ns);
        #pragma unroll
        for (int b = 0; b < NB; ++b) {
            float2 v0 = make_float2(sR[b][i0], sI[b][i0]);
            float2 v1 = cmulw<DIR>(make_float2(sR[b][i1], sI[b][i1]), w1);
            float2 v2 = cmulw<DIR>(make_float2(sR[b][i2], sI[b][i2]), w2);
            float2 v3 = cmulw<DIR>(make_float2(sR[b][i3], sI[b][i3]), w3);
            float2 t0 = make_float2(v0.x + v2.x, v0.y + v2.y);
            float2 t1 = make_float2(v0.x - v2.x, v0.y - v2.y);
            float2 t2 = make_float2(v1.x + v3.x, v1.y + v3.y);
            float2 t3 = make_float2(v1.x - v3.x, v1.y - v3.y);
            float2 y0 = make_float2(t0.x + t2.x, t0.y + t2.y);
            float2 y2 = make_float2(t0.x - t2.x, t0.y - t2.y);
            float2 y1, y3;
            if (DIR < 0) {
                y1 = make_float2(t1.x + t3.y, t1.y - t3.x);
                y3 = make_float2(t1.x - t3.y, t1.y + t3.x);
            } else {
                y1 = make_float2(t1.x - t3.y, t1.y + t3.x);
                y3 = make_float2(t1.x + t3.y, t1.y - t3.x);
            }
            dR[b][o0] = y0.x; dI[b][o0] = y0.y;
            dR[b][o1] = y1.x; dI[b][o1] = y1.y;
            dR[b][o2] = y2.x; dI[b][o2] = y2.y;
            dR[b][o3] = y3.x; dI[b][o3] = y3.y;
        }
        { auto tp = sR; sR = dR; dR = tp; }
        { auto tp = sI; sI = dI; dI = tp; }
        Ns <<= 2;
    }
    __syncthreads();
    #pragma unroll
    for (int q = 0; q < 2; ++q) {
        int j2 = t + q * 128;
        float2 w = tab[PT(j2)];
        int i0 = P5(j2), i1 = P5(j2 + 256);
        #pragma unroll
        for (int b = 0; b < NB; ++b) {
            float2 v0 = make_float2(sR[b][i0], sI[b][i0]);
            float2 tw = cmulw<DIR>(make_float2(sR[b][i1], sI[b][i1]), w);
            dR[b][i0] = v0.x + tw.x; dI[b][i0] = v0.y + tw.y;
            dR[b][i1] = v0.x - tw.x; dI[b][i1] = v0.y - tw.y;
        }
    }
    __syncthreads();
}

// ---------------------------------------------------------------------------
__global__ void k_zero(float* __restrict__ out, int n) {
    int i = blockIdx.x * 256 + threadIdx.x;
    int stride = gridDim.x * 256;
    for (; i < n; i += stride) out[i] = 0.f;
}

// ---------------------------------------------------------------------------
// Pass 1: block = (ca, x-quad). Modulate mps*x (L3-resident gathers), pad y,
// batch-4 forward y-FFTs, write bufA[ca][ky][x0..x0+3] (32B chunks; the
// sibling quad completes the 64B line).
// ---------------------------------------------------------------------------
__global__ void __launch_bounds__(128) k_fft1c(const float* __restrict__ xr_,
        const float* __restrict__ xi_, const float* __restrict__ mr_,
        const float* __restrict__ mi_) {
    __shared__ float AR[4][NPAD], AI[4][NPAD], BR[4][NPAD], BI[4][NPAD];
    __shared__ float2 tab[288];
    int bid = blockIdx.x;
    int ca = bid >> 6;
    int x0 = (bid & 63) << 2;
    int coil = ca / A_, a = ca % A_;
    int t = threadIdx.x;
    build_tab(tab, t);
    int xc = t & 3, yo = t >> 2;          // yo 0..31
    int xcol = x0 + xc;
    const float* xr = xr_ + a * 65536;
    const float* xi = xi_ + a * 65536;
    const float* mr = mr_ + coil * 65536;
    const float* mi = mi_ + coil * 65536;
    #pragma unroll
    for (int r = 0; r < 4; ++r) {         // zero pads y5 in [0,128)|[384,512)
        int z = yo + 32 * r;
        AR[xc][P5(z)] = 0.f;        AI[xc][P5(z)] = 0.f;
        AR[xc][P5(384 + z)] = 0.f;  AI[xc][P5(384 + z)] = 0.f;
    }
    #pragma unroll
    for (int r = 0; r < 8; ++r) {
        int y = yo + 32 * r;
        int idx = y * 256 + xcol;
        float xrv = xr[idx], xiv = xi[idx], mrv = mr[idx], miv = mi[idx];
        int p = P5(128 + y);
        AR[xc][p] = xrv * mrv - xiv * miv;
        AI[xc][p] = xrv * miv + xiv * mrv;
    }
    fftB<-1, 4>(AR, AI, BR, BI, tab, t);
    float2* o = g_bufA + (size_t)ca * 131072 + x0 + xc;
    #pragma unroll
    for (int rr = 0; rr < 16; ++rr) {
        int ky = yo + 32 * rr;
        int p = P5(ky);
        o[(size_t)ky * 256] = make_float2(BR[xc][p], BI[xc][p]);
    }
}

// ---------------------------------------------------------------------------
// Pass 2 (fused): per (coil,ky): batch-5 fwd x-FFTs + mix + batch-5 inv.
// ~13 barriers/block (was ~60). K native layout, XCD-pinned swizzle
// (R5-proven FETCH 58 MB), 2-deep software pipeline with compile-time
// buffer alternation (rule #20 safe).
// ---------------------------------------------------------------------------
#define KLOAD(KR, KI, q) { _Pragma("unroll")                                   \
    for (int m = 0; m < 25; ++m) {                                             \
        size_t idx = ((size_t)m << 18) + kyBase + (size_t)(t + (q) * 128);     \
        KR[m] = kr[idx]; KI[m] = ki[idx]; } }

#define MIXQ(KR, KI, q) { int p = P5(t + (q) * 128);                           \
    float fr[5], fi[5];                                                        \
    _Pragma("unroll") for (int ain = 0; ain < 5; ++ain) {                      \
        fr[ain] = F1R[ain][p]; fi[ain] = F1I[ain][p]; }                        \
    _Pragma("unroll") for (int ao = 0; ao < 5; ++ao) {                         \
        float gr = 0.f, gi = 0.f;                                              \
        _Pragma("unroll") for (int ain = 0; ain < 5; ++ain) {                  \
            float kre = KR[ao * 5 + ain], kim = KI[ao * 5 + ain];              \
            gr += kre * fr[ain] - kim * fi[ain];                               \
            gi += kre * fi[ain] + kim * fr[ain]; }                             \
        F1R[ao][p] = scale * gr; F1I[ao][p] = scale * gi; } }

__global__ void __launch_bounds__(128) k_colfmc(const float* __restrict__ kr,
                                                const float* __restrict__ ki) {
    __shared__ float F0R[5][NPAD], F0I[5][NPAD], F1R[5][NPAD], F1I[5][NPAD];
    __shared__ float2 tab[288];
    int b = blockIdx.x;
    int xcd = b & 7, s = b >> 3;          // bijective XCD-cluster swizzle
    int v = s / 96, wv = s % 96;
    int u = xcd + (v << 3);               // ky-octet 0..63
    int coil = wv % C_;
    int ky = (u << 3) + (wv / C_);
    int t = threadIdx.x;
    build_tab(tab, t);
    const float2* bA = g_bufA + (size_t)(coil * A_) * 131072 + ((size_t)ky << 8);
    float4 row[5];
    #pragma unroll
    for (int ain = 0; ain < 5; ++ain)     // 5 coalesced full rows in flight
        row[ain] = ((const float4*)(bA + (size_t)ain * 131072))[t];
    size_t kyBase = (size_t)ky << 9;
    float kRa[25], kIa[25], kRb[25], kIb[25];
    KLOAD(kRa, kIa, 0);                   // q=0 K in flight across the fwd FFT
    #pragma unroll
    for (int ain = 0; ain < 5; ++ain) {   // stage: pad + place x5 = x+128
        F0R[ain][P5(t)] = 0.f;        F0I[ain][P5(t)] = 0.f;
        F0R[ain][P5(t + 384)] = 0.f;  F0I[ain][P5(t + 384)] = 0.f;
        int p0 = P5(128 + 2 * t), p1 = P5(129 + 2 * t);
        F0R[ain][p0] = row[ain].x; F0I[ain][p0] = row[ain].y;
        F0R[ain][p1] = row[ain].z; F0I[ain][p1] = row[ain].w;
    }
    fftB<-1, 5>(F0R, F0I, F1R, F1I, tab, t);   // result in F1
    const float scale = 4.0f / 262144.0f;      // OVERSAMP^2 / (Hp*Wp)
    KLOAD(kRb, kIb, 1);
    MIXQ(kRa, kIa, 0);
    KLOAD(kRa, kIa, 2);
    MIXQ(kRb, kIb, 1);
    KLOAD(kRb, kIb, 3);
    MIXQ(kRa, kIa, 2);
    MIXQ(kRb, kIb, 3);
    fftB<1, 5>(F1R, F1I, F0R, F0I, tab, t);    // result in F0
    #pragma unroll
    for (int ao = 0; ao < 5; ++ao) {           // crop x5 in [128,384), full-line
        int p0 = P5(128 + 2 * t), p1 = P5(129 + 2 * t);
        float4 vv = make_float4(F0R[ao][p0], F0I[ao][p0],
                                F0R[ao][p1], F0I[ao][p1]);
        ((float4*)(g_bufB + (size_t)(coil * A_ + ao) * 131072 +
                   ((size_t)ky << 8)))[t] = vv;
    }
}

// ---------------------------------------------------------------------------
// Pass 3: block = (a, x-quad, coil-triplet). Batch-4 inverse ky-FFTs from
// bufB (L3-resident 32B chunks), crop y, conj(mps) reduce, atomicAdd into
// planar out (4 partial writers per address).
// ---------------------------------------------------------------------------
__global__ void __launch_bounds__(128) k_outfr(const float* __restrict__ mr_,
        const float* __restrict__ mi_, float* __restrict__ out, int outFloats) {
    __shared__ float AR[4][NPAD], AI[4][NPAD], BR[4][NPAD], BI[4][NPAD];
    __shared__ float2 tab[288];
    int bid = blockIdx.x;                 // 5 * 64 * 4 = 1280
    int a = bid >> 8;
    int x0 = ((bid >> 2) & 63) << 2;
    int cg = bid & 3;
    int t = threadIdx.x;
    build_tab(tab, t);
    int xc = t & 3, yo = t >> 2;          // yo 0..31
    int xcol = x0 + xc;
    float accR[8], accI[8];
    #pragma unroll
    for (int r = 0; r < 8; ++r) { accR[r] = 0.f; accI[r] = 0.f; }
    for (int cc = 0; cc < 3; ++cc) {
        int c = cg * 3 + cc;
        const float2* src = g_bufB + (size_t)(c * A_ + a) * 131072 + xcol;
        #pragma unroll
        for (int rr = 0; rr < 16; ++rr) { // stage 512 ky per xc
            int ky = yo + 32 * rr;
            float2 vv = src[(size_t)ky * 256];
            int p = P5(ky);
            AR[xc][p] = vv.x; AI[xc][p] = vv.y;
        }
        fftB<1, 4>(AR, AI, BR, BI, tab, t);    // head barrier orders staging
        const float* mr = mr_ + c * 65536;
        const float* mi = mi_ + c * 65536;
        #pragma unroll
        for (int rr = 0; rr < 8; ++rr) {       // crop y5 in [128,384)
            int y = yo + 32 * rr;
            int p = P5(128 + y);
            float vx = BR[xc][p], vy = BI[xc][p];
            int idx = y * 256 + xcol;
            float mrv = mr[idx], miv = mi[idx];
            accR[rr] += vx * mrv + vy * miv;   // v * conj(m)
            accI[rr] += vy * mrv - vx * miv;
        }
    }
    #pragma unroll
    for (int rr = 0; rr < 8; ++rr) {
        int y = yo + 32 * rr;
        size_t r0 = (size_t)a * 65536 + (size_t)y * 256 + xcol;
        size_t i0 = 327680 + r0;
        if (r0 < (size_t)outFloats) atomicAdd(&out[r0], accR[rr]);
        if (i0 < (size_t)outFloats) atomicAdd(&out[i0], accI[rr]);
    }
}

// ---------------------------------------------------------------------------
extern "C" void kernel_launch(void* const* d_in, const int* in_sizes, int n_in,
                              void* d_out, int out_size, void* d_ws, size_t ws_size,
                              hipStream_t stream) {
    const float* xr = (const float*)d_in[0];
    const float* xi = (const float*)d_in[1];
    const float* mr = (const float*)d_in[2];
    const float* mi = (const float*)d_in[3];
    const float* kr = (const float*)d_in[4];
    const float* ki = (const float*)d_in[5];
    float* out = (float*)d_out;
    (void)d_ws; (void)ws_size; (void)n_in; (void)in_sizes;

    int nz = out_size < 655360 ? out_size : 655360;   // floats to zero
    k_zero  <<<256, 256, 0, stream>>>(out, nz);
    k_fft1c <<<RPG * 64, 128, 0, stream>>>(xr, xi, mr, mi);
    k_colfmc<<<C_ * 512, 128, 0, stream>>>(kr, ki);
    k_outfr <<<A_ * 256, 128, 0, stream>>>(mr, mi, out, out_size);
}